// Round 1
// baseline (1038.104 us; speedup 1.0000x reference)
//
#include <hip/hip_runtime.h>
#include <math.h>

// Problem constants (fixed-shape harness):
constexpr int   Nn    = 8192;
constexpr int   FIN   = 256;
constexpr int   FOUT  = 64;
constexpr float ALPHA = 0.2f;       // LeakyReLU negative slope
constexpr float NEGB  = -9e15f;     // mask value (multiplied, per original module)
constexpr int   CAP   = 512;        // compact-list capacity; fallback path if exceeded

__device__ __forceinline__ float lrelu(float x) { return x >= 0.f ? x : ALPHA * x; }

// ---------------------------------------------------------------------------
// Kernel A: h = nodes @ W  [N, FOUT];  s_src = h @ a[:FOUT]; s_dst = h @ a[FOUT:]
// One block = 4 rows; wave w handles row w, lane = output column.
// ---------------------------------------------------------------------------
__global__ __launch_bounds__(256) void precompute_k(
    const float* __restrict__ nodes, const float* __restrict__ W,
    const float* __restrict__ a, float* __restrict__ h,
    float* __restrict__ s_src, float* __restrict__ s_dst) {
  __shared__ float nd[4][FIN];
  const int t    = threadIdx.x;
  const int row0 = blockIdx.x * 4;
  // stage 4 node rows (4 KB) coalesced
  for (int idx = t; idx < 4 * FIN; idx += 256)
    nd[idx >> 8][idx & 255] = nodes[(size_t)(row0 + (idx >> 8)) * FIN + (idx & 255)];
  __syncthreads();
  const int r = t >> 6;   // wave id == local row
  const int k = t & 63;   // output column
  const int i = row0 + r;
  float acc = 0.f;
#pragma unroll 8
  for (int c = 0; c < FIN; ++c)
    acc = fmaf(nd[r][c], W[c * FOUT + k], acc);   // W row read coalesced, L2-resident
  h[(size_t)i * FOUT + k] = acc;
  float sa = acc * a[k];
  float sb = acc * a[FOUT + k];
#pragma unroll
  for (int off = 32; off >= 1; off >>= 1) {
    sa += __shfl_xor(sa, off, 64);
    sb += __shfl_xor(sb, off, 64);
  }
  if (k == 0) { s_src[i] = sa; s_dst[i] = sb; }
}

// ---------------------------------------------------------------------------
// Kernel B: one workgroup (256 thr) per row i.
//   Phase 1: stream adj row (float4, coalesced), v_j = lrelu(ss+sd_j)*mask -> LDS, row max
//   Phase 2: p_j = exp(v_j - M) (overwrite LDS), sum, compact nonzeros (rare!)
//   Phase 3: out_k = lrelu( (sum_e p_e * h[j_e][k]) / L )
// ---------------------------------------------------------------------------
__global__ __launch_bounds__(256) void attn_k(
    const float* __restrict__ adj, const float* __restrict__ h,
    const float* __restrict__ s_src, const float* __restrict__ s_dst,
    float* __restrict__ out) {
  __shared__ __align__(16) float vals[Nn];   // 32 KB: scores, then probs
  __shared__ int   list_j[CAP];
  __shared__ float list_p[CAP];
  __shared__ float red[8];
  __shared__ float oscr[4 * FOUT];
  __shared__ int   cnt;

  const int t = threadIdx.x;
  const int i = blockIdx.x;
  if (t == 0) cnt = 0;

  const float  ss     = s_src[i];
  const float4* adjr  = (const float4*)(adj + (size_t)i * Nn);
  const float4* sd4   = (const float4*)s_dst;
  float4* vals4       = (float4*)vals;

  // ---- Phase 1: scores + max ----
  float vmax = -INFINITY;
#pragma unroll
  for (int it = 0; it < 8; ++it) {
    const int q = t + it * 256;          // float4 index
    float4 a4 = adjr[q];
    float4 s4 = sd4[q];
    float4 v;
    float tv;
    tv = ss + s4.x; tv = lrelu(tv); v.x = (a4.x > 0.5f) ? tv : tv * NEGB;
    tv = ss + s4.y; tv = lrelu(tv); v.y = (a4.y > 0.5f) ? tv : tv * NEGB;
    tv = ss + s4.z; tv = lrelu(tv); v.z = (a4.z > 0.5f) ? tv : tv * NEGB;
    tv = ss + s4.w; tv = lrelu(tv); v.w = (a4.w > 0.5f) ? tv : tv * NEGB;
    vals4[q] = v;
    vmax = fmaxf(vmax, fmaxf(fmaxf(v.x, v.y), fmaxf(v.z, v.w)));
  }
#pragma unroll
  for (int off = 32; off >= 1; off >>= 1)
    vmax = fmaxf(vmax, __shfl_xor(vmax, off, 64));
  if ((t & 63) == 0) red[t >> 6] = vmax;
  __syncthreads();
  const float M = fmaxf(fmaxf(red[0], red[1]), fmaxf(red[2], red[3]));

  // ---- Phase 2: exp, sum, compact nonzeros ----
  float lsum = 0.f;
#pragma unroll
  for (int it = 0; it < 8; ++it) {
    const int q = t + it * 256;
    float4 v = vals4[q];
    float4 p;
    p.x = expf(v.x - M);
    p.y = expf(v.y - M);
    p.z = expf(v.z - M);
    p.w = expf(v.w - M);
    vals4[q] = p;
    lsum += (p.x + p.y) + (p.z + p.w);
    if (p.x != 0.f || p.y != 0.f || p.z != 0.f || p.w != 0.f) {
      const int j = q * 4;
      if (p.x != 0.f) { int e = atomicAdd(&cnt, 1); if (e < CAP) { list_j[e] = j;     list_p[e] = p.x; } }
      if (p.y != 0.f) { int e = atomicAdd(&cnt, 1); if (e < CAP) { list_j[e] = j + 1; list_p[e] = p.y; } }
      if (p.z != 0.f) { int e = atomicAdd(&cnt, 1); if (e < CAP) { list_j[e] = j + 2; list_p[e] = p.z; } }
      if (p.w != 0.f) { int e = atomicAdd(&cnt, 1); if (e < CAP) { list_j[e] = j + 3; list_p[e] = p.w; } }
    }
  }
#pragma unroll
  for (int off = 32; off >= 1; off >>= 1)
    lsum += __shfl_xor(lsum, off, 64);
  if ((t & 63) == 0) red[4 + (t >> 6)] = lsum;
  __syncthreads();
  const float L = (red[4] + red[5]) + (red[6] + red[7]);
  const int   n = cnt;

  // ---- Phase 3: weighted gather of h rows ----
  const int g = t >> 6;   // wave id
  const int k = t & 63;   // output column
  float acc = 0.f;
  if (n <= CAP) {
    for (int e = g; e < n; e += 4)
      acc = fmaf(list_p[e], h[(size_t)list_j[e] * FOUT + k], acc);
  } else {
    // pathological fallback (never expected): full scan, probs are in vals[]
    for (int j = g; j < Nn; j += 4)
      acc = fmaf(vals[j], h[(size_t)j * FOUT + k], acc);
  }
  oscr[t] = acc;
  __syncthreads();
  if (t < 64) {
    float tot = ((oscr[t] + oscr[64 + t]) + (oscr[128 + t] + oscr[192 + t])) / L;
    out[(size_t)i * FOUT + t] = lrelu(tot);
  }
}

// ---------------------------------------------------------------------------
extern "C" void kernel_launch(void* const* d_in, const int* in_sizes, int n_in,
                              void* d_out, int out_size, void* d_ws, size_t ws_size,
                              hipStream_t stream) {
  const float* nodes = (const float*)d_in[0];
  const float* adj   = (const float*)d_in[1];
  const float* W     = (const float*)d_in[2];
  const float* a     = (const float*)d_in[3];
  float* out = (float*)d_out;

  // workspace layout: h [N*FOUT] | s_src [N] | s_dst [N]  (~2.06 MB)
  float* h     = (float*)d_ws;
  float* s_src = h + (size_t)Nn * FOUT;
  float* s_dst = s_src + Nn;

  precompute_k<<<Nn / 4, 256, 0, stream>>>(nodes, W, a, h, s_src, s_dst);
  attn_k<<<Nn, 256, 0, stream>>>(adj, h, s_src, s_dst, out);
}

// Round 2
// 848.272 us; speedup vs baseline: 1.2238x; 1.2238x over previous
//
#include <hip/hip_runtime.h>
#include <math.h>

// Problem constants (fixed-shape harness):
constexpr int   Nn    = 8192;
constexpr int   FIN   = 256;
constexpr int   FOUT  = 64;
constexpr float ALPHA = 0.2f;       // LeakyReLU negative slope
constexpr float NEGB  = -9e15f;     // mask value (multiplied, per original module)
constexpr float WWIN  = 110.f;      // exp(v-M)==0 exactly below M-104.5; margin to 110
constexpr int   CAP   = 128;        // candidate-list capacity (typical count: 1)

__device__ __forceinline__ float lrelu(float x) { return x >= 0.f ? x : ALPHA * x; }

// ---------------------------------------------------------------------------
// Kernel P1: h = nodes @ W  [N, FOUT]. Register-tiled 64x64 per block,
// 4x4 micro-tile per thread. fmaf chain over c ascending == previous kernel's
// order => bit-identical h.
// ---------------------------------------------------------------------------
__global__ __launch_bounds__(256) void gemm_h(
    const float* __restrict__ nodes, const float* __restrict__ W,
    float* __restrict__ h) {
  __shared__ __align__(16) float ndT[64 * 68];  // [c][r], padded
  __shared__ __align__(16) float Ws[64 * 68];   // [c][k], padded
  const int t  = threadIdx.x;
  const int r0 = blockIdx.x * 64;
  const int tx = t & 15;   // k-group: cols 4*tx..4*tx+3
  const int ty = t >> 4;   // r-group: rows 4*ty..4*ty+3
  float acc[4][4] = {{0.f}};

  for (int c0 = 0; c0 < FIN; c0 += 64) {
    // stage W chunk [64c][64k], coalesced
#pragma unroll
    for (int s = 0; s < 16; ++s) {
      const int cc = (t >> 6) + 4 * s;
      Ws[cc * 68 + (t & 63)] = W[(size_t)(c0 + cc) * FOUT + (t & 63)];
    }
    // stage nodes chunk transposed [64c][64r]
#pragma unroll
    for (int s = 0; s < 4; ++s) {
      const int rl = (t >> 4) + 16 * s;
      const float4 nv = *(const float4*)&nodes[(size_t)(r0 + rl) * FIN + c0 + (t & 15) * 4];
      const int cl = (t & 15) * 4;
      ndT[(cl + 0) * 68 + rl] = nv.x;
      ndT[(cl + 1) * 68 + rl] = nv.y;
      ndT[(cl + 2) * 68 + rl] = nv.z;
      ndT[(cl + 3) * 68 + rl] = nv.w;
    }
    __syncthreads();
#pragma unroll 8
    for (int cc = 0; cc < 64; ++cc) {
      const float4 a4 = *(const float4*)&ndT[cc * 68 + 4 * ty];
      const float4 b4 = *(const float4*)&Ws[cc * 68 + 4 * tx];
      const float av[4] = {a4.x, a4.y, a4.z, a4.w};
      const float bv[4] = {b4.x, b4.y, b4.z, b4.w};
#pragma unroll
      for (int ri = 0; ri < 4; ++ri)
#pragma unroll
        for (int ki = 0; ki < 4; ++ki)
          acc[ri][ki] = fmaf(av[ri], bv[ki], acc[ri][ki]);
    }
    __syncthreads();
  }
#pragma unroll
  for (int ri = 0; ri < 4; ++ri) {
    float4 o = make_float4(acc[ri][0], acc[ri][1], acc[ri][2], acc[ri][3]);
    *(float4*)&h[(size_t)(r0 + 4 * ty + ri) * FOUT + 4 * tx] = o;
  }
}

// ---------------------------------------------------------------------------
// Kernel P2: s_src = h@a[:F], s_dst = h@a[F:]. Same butterfly order as the
// previous passing kernel => bit-identical s.
// ---------------------------------------------------------------------------
__global__ __launch_bounds__(256) void scores_k(
    const float* __restrict__ h, const float* __restrict__ a,
    float* __restrict__ s_src, float* __restrict__ s_dst) {
  const int t = threadIdx.x;
  const int i = blockIdx.x * 4 + (t >> 6);
  const int k = t & 63;
  const float hv = h[(size_t)i * FOUT + k];
  float sa = hv * a[k];
  float sb = hv * a[FOUT + k];
#pragma unroll
  for (int off = 32; off >= 1; off >>= 1) {
    sa += __shfl_xor(sa, off, 64);
    sb += __shfl_xor(sb, off, 64);
  }
  if (k == 0) { s_src[i] = sa; s_dst[i] = sb; }
}

// ---------------------------------------------------------------------------
// Kernel B: one block (256 thr) per row. ONE streaming pass, no score
// staging: per-lane top-2 (v,j) + max-evicted tracker. Post survivors
// (v >= M-110) to a tiny LDS list; exp+gather. Exact fallback (second pass)
// if an evicted value could still matter or the list overflows.
// ---------------------------------------------------------------------------
__global__ __launch_bounds__(256) void attn_k(
    const float* __restrict__ adj, const float* __restrict__ h,
    const float* __restrict__ s_src, const float* __restrict__ s_dst,
    float* __restrict__ out) {
  __shared__ float redM[4], redE[4];
  __shared__ int   cnt;
  __shared__ float Lsh;
  __shared__ int   list_j[CAP];
  __shared__ float list_p[CAP];      // holds v, then p=exp(v-M)
  __shared__ float oscr[256];
  __shared__ __align__(16) float pbuf[1024];  // fallback only

  const int t = threadIdx.x;
  const int i = blockIdx.x;
  if (t == 0) cnt = 0;

  const float   ss   = s_src[i];
  const float4* adjr = (const float4*)(adj + (size_t)i * Nn);
  const float4* sd4  = (const float4*)s_dst;

  // ---- one-pass scan: per-lane top-2 + max-evicted ----
  float v1 = -INFINITY, v2 = -INFINITY, evm = -INFINITY;
  int   j1 = 0, j2 = 0;
#pragma unroll
  for (int it = 0; it < 8; ++it) {
    const int q = t + it * 256;            // float4 index
    const float4 a4 = adjr[q];
    const float4 s4 = sd4[q];
    const float av[4] = {a4.x, a4.y, a4.z, a4.w};
    const float sv[4] = {s4.x, s4.y, s4.z, s4.w};
    const int jb = q * 4;
#pragma unroll
    for (int u = 0; u < 4; ++u) {
      float tv = ss + sv[u];
      tv = tv >= 0.f ? tv : ALPHA * tv;
      const float v = (av[u] > 0.5f) ? tv : tv * NEGB;
      const bool g2 = v > v2;
      const bool g1 = v > v1;              // g1 implies g2 (v1 >= v2)
      evm = g2 ? fmaxf(evm, v2) : evm;     // value leaving the top-2
      const float ov1 = v1; const int oj1 = j1;
      v1 = g1 ? v : v1;
      j1 = g1 ? (jb + u) : j1;
      v2 = g1 ? ov1 : (g2 ? v : v2);
      j2 = g1 ? oj1 : (g2 ? (jb + u) : j2);
    }
  }

  // ---- block max of v1 (= M, exact) and of evm ----
  float m = v1, e = evm;
#pragma unroll
  for (int off = 32; off >= 1; off >>= 1) {
    m = fmaxf(m, __shfl_xor(m, off, 64));
    e = fmaxf(e, __shfl_xor(e, off, 64));
  }
  if ((t & 63) == 0) { redM[t >> 6] = m; redE[t >> 6] = e; }
  __syncthreads();
  const float M   = fmaxf(fmaxf(redM[0], redM[1]), fmaxf(redM[2], redM[3]));
  const float EV  = fmaxf(fmaxf(redE[0], redE[1]), fmaxf(redE[2], redE[3]));
  const float thr = M - WWIN;

  // ---- post surviving candidates ----
  if (v1 >= thr) { int p = atomicAdd(&cnt, 1); if (p < CAP) { list_j[p] = j1; list_p[p] = v1; } }
  if (v2 >= thr) { int p = atomicAdd(&cnt, 1); if (p < CAP) { list_j[p] = j2; list_p[p] = v2; } }
  __syncthreads();
  const int  n  = cnt;
  const bool fb = (EV >= thr) || (n > CAP);  // dropped candidate might matter

  const int g = t >> 6;   // wave id
  const int k = t & 63;   // output column
  float acc = 0.f;
  float Lv;

  if (!fb) {
    if (t < n) list_p[t] = expf(list_p[t] - M);
    __syncthreads();
    if (t == 0) { float L = 0.f; for (int q = 0; q < n; ++q) L += list_p[q]; Lsh = L; }
    for (int q = g; q < n; q += 4)
      acc = fmaf(list_p[q], h[(size_t)list_j[q] * FOUT + k], acc);
    __syncthreads();
    Lv = Lsh;
  } else {
    // exact fallback: full second pass (row is L2/L3-warm), dense PV
    float Lacc = 0.f;
    for (int base = 0; base < Nn; base += 1024) {
      const int q4 = (base >> 2) + t;
      const float4 a4 = adjr[q4];
      const float4 s4 = sd4[q4];
      const float av[4] = {a4.x, a4.y, a4.z, a4.w};
      const float sv[4] = {s4.x, s4.y, s4.z, s4.w};
      float pv[4];
#pragma unroll
      for (int u = 0; u < 4; ++u) {
        float tv = ss + sv[u];
        tv = tv >= 0.f ? tv : ALPHA * tv;
        const float v = (av[u] > 0.5f) ? tv : tv * NEGB;
        pv[u] = expf(v - M);
        Lacc += pv[u];
      }
      *(float4*)&pbuf[t * 4] = make_float4(pv[0], pv[1], pv[2], pv[3]);
      __syncthreads();
      for (int jj = g; jj < 1024; jj += 4)
        acc = fmaf(pbuf[jj], h[(size_t)(base + jj) * FOUT + k], acc);
      __syncthreads();
    }
#pragma unroll
    for (int off = 32; off >= 1; off >>= 1)
      Lacc += __shfl_xor(Lacc, off, 64);
    if ((t & 63) == 0) redM[t >> 6] = Lacc;
    __syncthreads();
    Lv = (redM[0] + redM[1]) + (redM[2] + redM[3]);
  }

  // ---- combine wave partials, normalize, activate (same order as before) ----
  oscr[t] = acc;
  __syncthreads();
  if (t < 64) {
    const float tot = ((oscr[t] + oscr[64 + t]) + (oscr[128 + t] + oscr[192 + t])) / Lv;
    out[(size_t)i * FOUT + t] = lrelu(tot);
  }
}

// ---------------------------------------------------------------------------
extern "C" void kernel_launch(void* const* d_in, const int* in_sizes, int n_in,
                              void* d_out, int out_size, void* d_ws, size_t ws_size,
                              hipStream_t stream) {
  const float* nodes = (const float*)d_in[0];
  const float* adj   = (const float*)d_in[1];
  const float* W     = (const float*)d_in[2];
  const float* a     = (const float*)d_in[3];
  float* out = (float*)d_out;

  // workspace: h [N*FOUT] | s_src [N] | s_dst [N]  (~2.13 MB)
  float* h     = (float*)d_ws;
  float* s_src = h + (size_t)Nn * FOUT;
  float* s_dst = s_src + Nn;

  gemm_h  <<<Nn / 64, 256, 0, stream>>>(nodes, W, h);
  scores_k<<<Nn / 4,  256, 0, stream>>>(h, a, s_src, s_dst);
  attn_k  <<<Nn,      256, 0, stream>>>(adj, h, s_src, s_dst, out);
}